// Round 5
// baseline (294.243 us; speedup 1.0000x reference)
//
#include <hip/hip_runtime.h>
#include <math.h>

#define EPSF 1e-8f
#define SINH_MAXF 11.090354888959125f
#define IMAGE_ALPHA 0.25f
#define TEXT_ALPHA (1.0f/0.6f)
#define LOGIT_SCALE (1.0f/0.07f)
#define LN2F 0.6931471805599453f
#define SLN (LOGIT_SCALE*LN2F)
#define ENTAIL_WEIGHT 0.2f
#define NCLS 151
#define NPAD 160
#define DIM 64
#define NBLK 1024   // 16 waves/block, 32 pixels/wave, 512 pixels/block

// ws float offsets
#define LMIN_OFF 8   // log2(2*min_c y_time)
#define YT_OFF 16
#define XN_OFF (YT_OFF + NPAD)
#define AP_OFF (XN_OFF + NPAD)
#define BT_OFF 512                    // bf16 protos, MFMA-fragment order, 20480 B
#define BLK_OFF (BT_OFF + NPAD*DIM/2) // per-block float4 partials

// native exp2 (v_exp_f32) if the builtin exists; otherwise equivalent fallback
#if __has_builtin(__builtin_amdgcn_exp2f)
#define EXP2F(x) __builtin_amdgcn_exp2f(x)
#else
#define EXP2F(x) __expf((x) * LN2F)
#endif

typedef __attribute__((ext_vector_type(8))) short bf16x8;
typedef __attribute__((ext_vector_type(4))) float f32x4;

__device__ inline unsigned short f2bf(float f) {      // RNE (cold path only)
    unsigned int u = __float_as_uint(f);
    return (unsigned short)((u + 0x7FFFu + ((u >> 16) & 1u)) >> 16);
}
// pack trunc-bf16(hi) , trunc-bf16(lo) into one dword: 1 v_perm_b32
__device__ inline unsigned int pack_bf_trunc(float hi, float lo) {
    return __builtin_amdgcn_perm(__float_as_uint(hi), __float_as_uint(lo), 0x07060302u);
}
__device__ inline float sel4(const float* a, int i) {
    return i == 0 ? a[0] : i == 1 ? a[1] : i == 2 ? a[2] : a[3];
}
__device__ inline int isel4(const int* a, int i) {
    return i == 0 ? a[0] : i == 1 ? a[1] : i == 2 ? a[2] : a[3];
}

// Single block, 16 lanes per class. Writes protos in MFMA B-fragment order:
// 16B unit index = t*128 + half*64 + (g*16+cn), element j: class t*16+cn, dim half*32+g*8+j
// Lane li (0..15) of class group owns dims li*4..li*4+3:
//   half = li>>3, g = (li>>1)&3, j0 = (li&1)*4  ->  two dwords at unit*4 + (li&1)*2
__global__ __launch_bounds__(256) void proto_kernel(const float* __restrict__ protos,
                                                    float* __restrict__ ws) {
    int tid = threadIdx.x;
    int grp = tid >> 4, li = tid & 15;
    unsigned int* btu = (unsigned int*)(ws + BT_OFF);
    __shared__ float sYT[NPAD];
    #pragma unroll 2
    for (int t = 0; t < 10; t++) {
        int c = t * 16 + grp;
        float4 p4 = make_float4(0.f, 0.f, 0.f, 0.f);
        if (c < NCLS) p4 = ((const float4*)protos)[c * 16 + li];
        float vx = p4.x * TEXT_ALPHA, vy = p4.y * TEXT_ALPHA,
              vz = p4.z * TEXT_ALPHA, vw = p4.w * TEXT_ALPHA;
        float n2 = vx*vx + vy*vy + vz*vz + vw*vw;
        #pragma unroll
        for (int m = 8; m >= 1; m >>= 1) n2 += __shfl_xor(n2, m, 64);
        float rc = __builtin_amdgcn_sqrtf(n2);
        float rr = fminf(fmaxf(rc, EPSF), SINH_MAXF);
        float e = __expf(rr);
        float sh = 0.5f * (e - __builtin_amdgcn_rcpf(e));
        float sc = sh * __builtin_amdgcn_rcpf(fmaxf(rc, EPSF));
        unsigned int u0, u1;
        float yt, xn, ap;
        if (c < NCLS) {
            u0 = (unsigned int)f2bf(sc * vx) | ((unsigned int)f2bf(sc * vy) << 16);
            u1 = (unsigned int)f2bf(sc * vz) | ((unsigned int)f2bf(sc * vw) << 16);
            xn = sc * rc;
            yt = __builtin_amdgcn_sqrtf(fmaf(xn, xn, 1.f));
            float ai = fminf(fmaxf(0.2f / (xn + EPSF), -1.f + EPSF), 1.f - EPSF);
            ap = asinf(ai);
        } else {
            u0 = 0u; u1 = 0u; yt = 2e18f; xn = 1.f; ap = 0.f;
        }
        int unit = t * 128 + (li >> 3) * 64 + ((li >> 1) & 3) * 16 + grp;
        btu[unit * 4 + (li & 1) * 2]     = u0;
        btu[unit * 4 + (li & 1) * 2 + 1] = u1;
        if (li == 0) {
            ws[YT_OFF + c] = yt; ws[XN_OFF + c] = xn; ws[AP_OFF + c] = ap;
            sYT[c] = yt;
        }
    }
    __syncthreads();
    if (tid < 64) {
        float m = 1e30f;
        for (int c = tid; c < NCLS; c += 64) m = fminf(m, sYT[c]);
        #pragma unroll
        for (int k = 32; k >= 1; k >>= 1) m = fminf(m, __shfl_xor(m, k, 64));
        if (tid == 0) ws[LMIN_OFF] = __log2f(2.f * m);
    }
}

struct PixA { bf16x8 q0, q1; float xt, Q; };

__device__ inline PixA stage_pixel(const float4* fp, float lmin2) {
    float4 f0 = fp[0], f1 = fp[1], f2 = fp[8], f3 = fp[9];   // raw feats
    float n2r = f0.x*f0.x + f0.y*f0.y + f0.z*f0.z + f0.w*f0.w
              + f1.x*f1.x + f1.y*f1.y + f1.z*f1.z + f1.w*f1.w
              + f2.x*f2.x + f2.y*f2.y + f2.z*f2.z + f2.w*f2.w
              + f3.x*f3.x + f3.y*f3.y + f3.z*f3.z + f3.w*f3.w;
    n2r += __shfl_xor(n2r, 16, 64);
    n2r += __shfl_xor(n2r, 32, 64);      // 4 owner-lanes of this pixel have full ||feat||^2
    float rc = IMAGE_ALPHA * __builtin_amdgcn_sqrtf(n2r);   // ||alpha*feat||
    float rr = fminf(fmaxf(rc, EPSF), SINH_MAXF);
    float e = __expf(rr);
    float sh = 0.5f * (e - __builtin_amdgcn_rcpf(e));
    float sc = sh * __builtin_amdgcn_rcpf(fmaxf(rc, EPSF));
    float xn = sc * rc;
    float k = sc * IMAGE_ALPHA;          // combined scale on raw feats
    PixA r;
    r.xt = __builtin_amdgcn_sqrtf(fmaf(xn, xn, 1.f));
    // log2-domain constant: Q2 = (M0 - SLN)/ln2 so inner eval is one native exp2
    r.Q = LOGIT_SCALE * (lmin2 - __log2f(r.xt + xn) - 1.0f);
    unsigned int* q0u = (unsigned int*)&r.q0;
    unsigned int* q1u = (unsigned int*)&r.q1;
    q0u[0] = pack_bf_trunc(k*f0.y, k*f0.x);
    q0u[1] = pack_bf_trunc(k*f0.w, k*f0.z);
    q0u[2] = pack_bf_trunc(k*f1.y, k*f1.x);
    q0u[3] = pack_bf_trunc(k*f1.w, k*f1.z);
    q1u[0] = pack_bf_trunc(k*f2.y, k*f2.x);
    q1u[1] = pack_bf_trunc(k*f2.w, k*f2.z);
    q1u[2] = pack_bf_trunc(k*f3.y, k*f3.x);
    q1u[3] = pack_bf_trunc(k*f3.w, k*f3.z);
    return r;
}

// 1024 threads = 16 waves; one LDS staging serves all 16; 2 blocks/CU resident
// (43 KB LDS, 64-VGPR cap) -> 32 waves/CU, vs ~12 at the 256-thread geometry.
__global__ __launch_bounds__(1024, 8) void main_kernel(
    const float* __restrict__ feats, const int* __restrict__ labels,
    const unsigned char* __restrict__ mask, const float* __restrict__ wsro,
    float4* __restrict__ blkout)
{
    __shared__ uint4 sBT[1280];     // 20480 B, fragment order
    __shared__ float sYT[NPAD];
    int tid = threadIdx.x;
    const uint4* btg = (const uint4*)(wsro + BT_OFF);
    if (tid < 256) {
        #pragma unroll
        for (int k = 0; k < 5; k++) sBT[tid + k * 256] = btg[tid + k * 256];
        if (tid < NPAD) sYT[tid] = wsro[YT_OFF + tid];
    }
    __syncthreads();

    int wid = tid >> 6, lane = tid & 63;
    int cn = lane & 15, g = lane >> 4;
    int wavebase = (blockIdx.x * 16 + wid) * 32;
    int pix0 = wavebase + cn, pix1 = pix0 + 16;
    float lmin2 = wsro[LMIN_OFF];

    PixA A0 = stage_pixel((const float4*)(feats + (size_t)pix0 * DIM + g * 8), lmin2);
    PixA A1 = stage_pixel((const float4*)(feats + (size_t)pix1 * DIM + g * 8), lmin2);
    int lab0 = labels[pix0], lab1 = labels[pix1];

    float xtr0[4], Q0[4], xtr1[4], Q1[4];
    int lr0[4], lr1[4];
    #pragma unroll
    for (int r = 0; r < 4; r++) {
        int src = g * 4 + r;
        xtr0[r] = __shfl(A0.xt, src, 64); Q0[r] = __shfl(A0.Q, src, 64);
        lr0[r]  = __shfl(lab0, src, 64);
        xtr1[r] = __shfl(A1.xt, src, 64); Q1[r] = __shfl(A1.Q, src, 64);
        lr1[r]  = __shfl(lab1, src, 64);
    }

    float ss0[4] = {0,0,0,0}, ss1[4] = {0,0,0,0};
    float sv0[4] = {0,0,0,0}, sv1[4] = {0,0,0,0};   // label-z saved on owning lane

    #pragma unroll 2
    for (int t = 0; t < 10; t++) {
        uint4 u0 = sBT[t * 128 + lane];
        uint4 u1 = sBT[t * 128 + 64 + lane];
        bf16x8 bq0 = __builtin_bit_cast(bf16x8, u0);
        bf16x8 bq1 = __builtin_bit_cast(bf16x8, u1);
        float yt = sYT[t * 16 + cn];
        int cls = t * 16 + cn;
        f32x4 d0 = {0,0,0,0}, d1 = {0,0,0,0};
        d0 = __builtin_amdgcn_mfma_f32_16x16x32_bf16(A0.q0, bq0, d0, 0, 0, 0);
        d0 = __builtin_amdgcn_mfma_f32_16x16x32_bf16(A0.q1, bq1, d0, 0, 0, 0);
        d1 = __builtin_amdgcn_mfma_f32_16x16x32_bf16(A1.q0, bq0, d1, 0, 0, 0);
        d1 = __builtin_amdgcn_mfma_f32_16x16x32_bf16(A1.q1, bq1, d1, 0, 0, 0);
        #pragma unroll
        for (int r = 0; r < 4; r++) {
            float c0 = fmaf(xtr0[r], yt, -d0[r]);     // z = x_time*y_time - dot
            if (lr0[r] == cls) sv0[r] = c0;
            ss0[r] += EXP2F(fmaf(-LOGIT_SCALE, __log2f(c0), Q0[r]));  // 2^(logit2 - M02)
            float c1 = fmaf(xtr1[r], yt, -d1[r]);
            if (lr1[r] == cls) sv1[r] = c1;
            ss1[r] += EXP2F(fmaf(-LOGIT_SCALE, __log2f(c1), Q1[r]));
        }
    }

    // sum-reduce ss across the 16-lane class dim; fetch label-z via shfl gather
    int gbase = lane & 48;
    float cx0[4], cx1[4];
    #pragma unroll
    for (int r = 0; r < 4; r++) {
        cx0[r] = __shfl(sv0[r], gbase + (lr0[r] & 15), 64);
        cx1[r] = __shfl(sv1[r], gbase + (lr1[r] & 15), 64);
    }
    #pragma unroll
    for (int k = 1; k < 16; k <<= 1) {
        #pragma unroll
        for (int r = 0; r < 4; r++) {
            ss0[r] += __shfl_xor(ss0[r], k, 64);
            ss1[r] += __shfl_xor(ss1[r], k, 64);
        }
    }

    float v_nll = 0.f, v_ent = 0.f, valid = 0.f;
    if (cn < 4) {
        #pragma unroll
        for (int tile = 0; tile < 2; tile++) {
            float T   = tile ? sel4(ss1, cn) : sel4(ss0, cn);
            float cxl = tile ? sel4(cx1, cn) : sel4(cx0, cn);
            float xts = tile ? sel4(xtr1, cn) : sel4(xtr0, cn);
            float Q   = tile ? sel4(Q1, cn) : sel4(Q0, cn);
            int lb    = tile ? isel4(lr1, cn) : isel4(lr0, cn);
            int pr = wavebase + g * 4 + cn + tile * 16;
            // nll = ln2 * (log2 T - Q2 + LS*log2 z_lab)
            float nll = LN2F * (__log2f(T) - Q + LOGIT_SCALE * __log2f(cxl));
            float pt = wsro[YT_OFF + lb], pn = wsro[XN_OFF + lb], ap = wsro[AP_OFF + lb];
            float num = fmaf(-cxl, pt, xts);              // y_time + c_xyl*x_time
            float den = pn * __builtin_amdgcn_sqrtf(fmaxf(fmaf(cxl, cxl, -1.f), 0.f));
            float ain = num * __builtin_amdgcn_rcpf(den + EPSF);
            ain = fminf(fmaxf(ain, -1.f + EPSF), 1.f - EPSF);
            // branchless acos: A&S 4.4.45, |err| <= 6.7e-5 rad
            float ax = fabsf(ain);
            float p = fmaf(fmaf(fmaf(-0.0187293f, ax, 0.0742610f), ax, -0.2121144f),
                           ax, 1.5707288f);
            float rr = __builtin_amdgcn_sqrtf(1.f - ax) * p;
            float ac = ain < 0.f ? 3.14159265358979f - rr : rr;
            float ent = fmaxf(ac - ap, 0.f);
            float vl = mask[pr] ? 0.f : 1.f;
            v_nll += nll * vl; v_ent += ent * vl; valid += vl;
        }
    }

    #pragma unroll
    for (int o = 32; o >= 1; o >>= 1) {
        v_nll += __shfl_down(v_nll, o, 64);
        v_ent += __shfl_down(v_ent, o, 64);
        valid += __shfl_down(valid, o, 64);
    }
    __shared__ float red[3][16];
    if (lane == 0) { red[0][wid] = v_nll; red[1][wid] = v_ent; red[2][wid] = valid; }
    __syncthreads();
    if (tid == 0) {
        float a = 0.f, b = 0.f, c = 0.f;
        #pragma unroll
        for (int w = 0; w < 16; w++) { a += red[0][w]; b += red[1][w]; c += red[2][w]; }
        blkout[blockIdx.x] = make_float4(a, b, c, 0.f);
    }
}

__global__ __launch_bounds__(1024) void reduce_kernel(const float4* __restrict__ blk,
                                                      float* __restrict__ out) {
    float a = 0.f, b = 0.f, c = 0.f;
    for (int i = threadIdx.x; i < NBLK; i += 1024) {
        float4 v = blk[i];
        a += v.x; b += v.y; c += v.z;
    }
    #pragma unroll
    for (int o = 32; o >= 1; o >>= 1) {
        a += __shfl_down(a, o, 64);
        b += __shfl_down(b, o, 64);
        c += __shfl_down(c, o, 64);
    }
    __shared__ float red[3][16];
    int wid = threadIdx.x >> 6, lane = threadIdx.x & 63;
    if (lane == 0) { red[0][wid] = a; red[1][wid] = b; red[2][wid] = c; }
    __syncthreads();
    if (threadIdx.x == 0) {
        float A = 0.f, B = 0.f, C = 0.f;
        #pragma unroll
        for (int w = 0; w < 16; w++) { A += red[0][w]; B += red[1][w]; C += red[2][w]; }
        float n = fmaxf(C, 1.f);
        out[0] = A / n + ENTAIL_WEIGHT * (B / n);
    }
}

extern "C" void kernel_launch(void* const* d_in, const int* in_sizes, int n_in,
                              void* d_out, int out_size, void* d_ws, size_t ws_size,
                              hipStream_t stream) {
    const float* feats  = (const float*)d_in[0];
    const float* protos = (const float*)d_in[1];
    const int* labels   = (const int*)d_in[2];
    const unsigned char* mask = (const unsigned char*)d_in[3];  // numpy bool = 1 byte
    float* ws = (float*)d_ws;

    proto_kernel<<<1, 256, 0, stream>>>(protos, ws);

    int npix = in_sizes[2];                 // B*H*W = 524288
    int nblk = npix / 512;                  // 16 waves/block, 32 pixels/wave
    main_kernel<<<nblk, 1024, 0, stream>>>(feats, labels, mask, ws,
                                           (float4*)(ws + BLK_OFF));
    reduce_kernel<<<1, 1024, 0, stream>>>((const float4*)(ws + BLK_OFF), (float*)d_out);
}

// Round 6
// 224.939 us; speedup vs baseline: 1.3081x; 1.3081x over previous
//
#include <hip/hip_runtime.h>
#include <math.h>

#define EPSF 1e-8f
#define SINH_MAXF 11.090354888959125f
#define IMAGE_ALPHA 0.25f
#define TEXT_ALPHA (1.0f/0.6f)
#define LOGIT_SCALE (1.0f/0.07f)
#define LN2F 0.6931471805599453f
#define SLN (LOGIT_SCALE*LN2F)
#define ENTAIL_WEIGHT 0.2f
#define NCLS 151
#define NPAD 160
#define DIM 64
#define NBLK 1024   // 16 waves/block, 32 pixels/wave, 512 pixels/block

// ws float offsets
#define LMIN_OFF 8   // log2(2*min_c y_time)
#define YT_OFF 16
#define XN_OFF (YT_OFF + NPAD)
#define AP_OFF (XN_OFF + NPAD)
#define BT_OFF 512                    // bf16 protos, MFMA-fragment order, 20480 B
#define BLK_OFF (BT_OFF + NPAD*DIM/2) // per-block float4 partials

// native exp2 (v_exp_f32) if the builtin exists; otherwise equivalent fallback
#if __has_builtin(__builtin_amdgcn_exp2f)
#define EXP2F(x) __builtin_amdgcn_exp2f(x)
#else
#define EXP2F(x) __expf((x) * LN2F)
#endif

typedef __attribute__((ext_vector_type(8))) short bf16x8;
typedef __attribute__((ext_vector_type(4))) float f32x4;

__device__ inline unsigned short f2bf(float f) {      // RNE (cold path only)
    unsigned int u = __float_as_uint(f);
    return (unsigned short)((u + 0x7FFFu + ((u >> 16) & 1u)) >> 16);
}
// pack trunc-bf16(hi) , trunc-bf16(lo) into one dword: 1 v_perm_b32
__device__ inline unsigned int pack_bf_trunc(float hi, float lo) {
    return __builtin_amdgcn_perm(__float_as_uint(hi), __float_as_uint(lo), 0x07060302u);
}
__device__ inline float sel4(const float* a, int i) {
    return i == 0 ? a[0] : i == 1 ? a[1] : i == 2 ? a[2] : a[3];
}
__device__ inline int isel4(const int* a, int i) {
    return i == 0 ? a[0] : i == 1 ? a[1] : i == 2 ? a[2] : a[3];
}

// Single block, 16 lanes per class. Writes protos in MFMA B-fragment order:
// 16B unit index = t*128 + half*64 + (g*16+cn), element j: class t*16+cn, dim half*32+g*8+j
// Lane li (0..15) of class group owns dims li*4..li*4+3:
//   half = li>>3, g = (li>>1)&3, j0 = (li&1)*4  ->  two dwords at unit*4 + (li&1)*2
__global__ __launch_bounds__(256) void proto_kernel(const float* __restrict__ protos,
                                                    float* __restrict__ ws) {
    int tid = threadIdx.x;
    int grp = tid >> 4, li = tid & 15;
    unsigned int* btu = (unsigned int*)(ws + BT_OFF);
    __shared__ float sYT[NPAD];
    #pragma unroll 2
    for (int t = 0; t < 10; t++) {
        int c = t * 16 + grp;
        float4 p4 = make_float4(0.f, 0.f, 0.f, 0.f);
        if (c < NCLS) p4 = ((const float4*)protos)[c * 16 + li];
        float vx = p4.x * TEXT_ALPHA, vy = p4.y * TEXT_ALPHA,
              vz = p4.z * TEXT_ALPHA, vw = p4.w * TEXT_ALPHA;
        float n2 = vx*vx + vy*vy + vz*vz + vw*vw;
        #pragma unroll
        for (int m = 8; m >= 1; m >>= 1) n2 += __shfl_xor(n2, m, 64);
        float rc = __builtin_amdgcn_sqrtf(n2);
        float rr = fminf(fmaxf(rc, EPSF), SINH_MAXF);
        float e = __expf(rr);
        float sh = 0.5f * (e - __builtin_amdgcn_rcpf(e));
        float sc = sh * __builtin_amdgcn_rcpf(fmaxf(rc, EPSF));
        unsigned int u0, u1;
        float yt, xn, ap;
        if (c < NCLS) {
            u0 = (unsigned int)f2bf(sc * vx) | ((unsigned int)f2bf(sc * vy) << 16);
            u1 = (unsigned int)f2bf(sc * vz) | ((unsigned int)f2bf(sc * vw) << 16);
            xn = sc * rc;
            yt = __builtin_amdgcn_sqrtf(fmaf(xn, xn, 1.f));
            float ai = fminf(fmaxf(0.2f / (xn + EPSF), -1.f + EPSF), 1.f - EPSF);
            ap = asinf(ai);
        } else {
            u0 = 0u; u1 = 0u; yt = 2e18f; xn = 1.f; ap = 0.f;
        }
        int unit = t * 128 + (li >> 3) * 64 + ((li >> 1) & 3) * 16 + grp;
        btu[unit * 4 + (li & 1) * 2]     = u0;
        btu[unit * 4 + (li & 1) * 2 + 1] = u1;
        if (li == 0) {
            ws[YT_OFF + c] = yt; ws[XN_OFF + c] = xn; ws[AP_OFF + c] = ap;
            sYT[c] = yt;
        }
    }
    __syncthreads();
    if (tid < 64) {
        float m = 1e30f;
        for (int c = tid; c < NCLS; c += 64) m = fminf(m, sYT[c]);
        #pragma unroll
        for (int k = 32; k >= 1; k >>= 1) m = fminf(m, __shfl_xor(m, k, 64));
        if (tid == 0) ws[LMIN_OFF] = __log2f(2.f * m);
    }
}

struct PixA { bf16x8 q0, q1; float xt, Q; };

__device__ inline PixA stage_pixel(const float4* fp, float lmin2) {
    float4 f0 = fp[0], f1 = fp[1], f2 = fp[8], f3 = fp[9];   // raw feats
    float n2r = f0.x*f0.x + f0.y*f0.y + f0.z*f0.z + f0.w*f0.w
              + f1.x*f1.x + f1.y*f1.y + f1.z*f1.z + f1.w*f1.w
              + f2.x*f2.x + f2.y*f2.y + f2.z*f2.z + f2.w*f2.w
              + f3.x*f3.x + f3.y*f3.y + f3.z*f3.z + f3.w*f3.w;
    n2r += __shfl_xor(n2r, 16, 64);
    n2r += __shfl_xor(n2r, 32, 64);      // 4 owner-lanes of this pixel have full ||feat||^2
    float rc = IMAGE_ALPHA * __builtin_amdgcn_sqrtf(n2r);   // ||alpha*feat||
    float rr = fminf(fmaxf(rc, EPSF), SINH_MAXF);
    float e = __expf(rr);
    float sh = 0.5f * (e - __builtin_amdgcn_rcpf(e));
    float sc = sh * __builtin_amdgcn_rcpf(fmaxf(rc, EPSF));
    float xn = sc * rc;
    float k = sc * IMAGE_ALPHA;          // combined scale on raw feats
    PixA r;
    r.xt = __builtin_amdgcn_sqrtf(fmaf(xn, xn, 1.f));
    // log2-domain constant: Q2 = (M0 - SLN)/ln2 so inner eval is one native exp2
    r.Q = LOGIT_SCALE * (lmin2 - __log2f(r.xt + xn) - 1.0f);
    unsigned int* q0u = (unsigned int*)&r.q0;
    unsigned int* q1u = (unsigned int*)&r.q1;
    q0u[0] = pack_bf_trunc(k*f0.y, k*f0.x);
    q0u[1] = pack_bf_trunc(k*f0.w, k*f0.z);
    q0u[2] = pack_bf_trunc(k*f1.y, k*f1.x);
    q0u[3] = pack_bf_trunc(k*f1.w, k*f1.z);
    q1u[0] = pack_bf_trunc(k*f2.y, k*f2.x);
    q1u[1] = pack_bf_trunc(k*f2.w, k*f2.z);
    q1u[2] = pack_bf_trunc(k*f3.y, k*f3.x);
    q1u[3] = pack_bf_trunc(k*f3.w, k*f3.z);
    return r;
}

// 1024 threads = 16 waves; one LDS staging serves all 16.
// R5 lesson: (1024, 8) forced VGPR to 32 -> ~140 MB of spill traffic, main 148 us.
// (1024, 4) caps at 128 under the compiler model; body needs ~60 -> no spill,
// and emitted <=64 VGPR still lets HW co-schedule 2 blocks/CU = 32 waves/CU.
__global__ __launch_bounds__(1024, 4) void main_kernel(
    const float* __restrict__ feats, const int* __restrict__ labels,
    const unsigned char* __restrict__ mask, const float* __restrict__ wsro,
    float4* __restrict__ blkout)
{
    __shared__ uint4 sBT[1280];     // 20480 B, fragment order
    __shared__ float sYT[NPAD];
    int tid = threadIdx.x;
    const uint4* btg = (const uint4*)(wsro + BT_OFF);
    if (tid < 256) {
        #pragma unroll
        for (int k = 0; k < 5; k++) sBT[tid + k * 256] = btg[tid + k * 256];
        if (tid < NPAD) sYT[tid] = wsro[YT_OFF + tid];
    }
    __syncthreads();

    int wid = tid >> 6, lane = tid & 63;
    int cn = lane & 15, g = lane >> 4;
    int wavebase = (blockIdx.x * 16 + wid) * 32;
    int pix0 = wavebase + cn, pix1 = pix0 + 16;
    float lmin2 = wsro[LMIN_OFF];

    PixA A0 = stage_pixel((const float4*)(feats + (size_t)pix0 * DIM + g * 8), lmin2);
    PixA A1 = stage_pixel((const float4*)(feats + (size_t)pix1 * DIM + g * 8), lmin2);
    int lab0 = labels[pix0], lab1 = labels[pix1];

    float xtr0[4], Q0[4], xtr1[4], Q1[4];
    int lr0[4], lr1[4];
    #pragma unroll
    for (int r = 0; r < 4; r++) {
        int src = g * 4 + r;
        xtr0[r] = __shfl(A0.xt, src, 64); Q0[r] = __shfl(A0.Q, src, 64);
        lr0[r]  = __shfl(lab0, src, 64);
        xtr1[r] = __shfl(A1.xt, src, 64); Q1[r] = __shfl(A1.Q, src, 64);
        lr1[r]  = __shfl(lab1, src, 64);
    }

    float ss0[4] = {0,0,0,0}, ss1[4] = {0,0,0,0};
    float sv0[4] = {0,0,0,0}, sv1[4] = {0,0,0,0};   // label-z saved on owning lane

    #pragma unroll 2
    for (int t = 0; t < 10; t++) {
        uint4 u0 = sBT[t * 128 + lane];
        uint4 u1 = sBT[t * 128 + 64 + lane];
        bf16x8 bq0 = __builtin_bit_cast(bf16x8, u0);
        bf16x8 bq1 = __builtin_bit_cast(bf16x8, u1);
        float yt = sYT[t * 16 + cn];
        int cls = t * 16 + cn;
        f32x4 d0 = {0,0,0,0}, d1 = {0,0,0,0};
        d0 = __builtin_amdgcn_mfma_f32_16x16x32_bf16(A0.q0, bq0, d0, 0, 0, 0);
        d0 = __builtin_amdgcn_mfma_f32_16x16x32_bf16(A0.q1, bq1, d0, 0, 0, 0);
        d1 = __builtin_amdgcn_mfma_f32_16x16x32_bf16(A1.q0, bq0, d1, 0, 0, 0);
        d1 = __builtin_amdgcn_mfma_f32_16x16x32_bf16(A1.q1, bq1, d1, 0, 0, 0);
        #pragma unroll
        for (int r = 0; r < 4; r++) {
            float c0 = fmaf(xtr0[r], yt, -d0[r]);     // z = x_time*y_time - dot
            if (lr0[r] == cls) sv0[r] = c0;
            ss0[r] += EXP2F(fmaf(-LOGIT_SCALE, __log2f(c0), Q0[r]));  // 2^(logit2 - M02)
            float c1 = fmaf(xtr1[r], yt, -d1[r]);
            if (lr1[r] == cls) sv1[r] = c1;
            ss1[r] += EXP2F(fmaf(-LOGIT_SCALE, __log2f(c1), Q1[r]));
        }
    }

    // sum-reduce ss across the 16-lane class dim; fetch label-z via shfl gather
    int gbase = lane & 48;
    float cx0[4], cx1[4];
    #pragma unroll
    for (int r = 0; r < 4; r++) {
        cx0[r] = __shfl(sv0[r], gbase + (lr0[r] & 15), 64);
        cx1[r] = __shfl(sv1[r], gbase + (lr1[r] & 15), 64);
    }
    #pragma unroll
    for (int k = 1; k < 16; k <<= 1) {
        #pragma unroll
        for (int r = 0; r < 4; r++) {
            ss0[r] += __shfl_xor(ss0[r], k, 64);
            ss1[r] += __shfl_xor(ss1[r], k, 64);
        }
    }

    float v_nll = 0.f, v_ent = 0.f, valid = 0.f;
    if (cn < 4) {
        #pragma unroll
        for (int tile = 0; tile < 2; tile++) {
            float T   = tile ? sel4(ss1, cn) : sel4(ss0, cn);
            float cxl = tile ? sel4(cx1, cn) : sel4(cx0, cn);
            float xts = tile ? sel4(xtr1, cn) : sel4(xtr0, cn);
            float Q   = tile ? sel4(Q1, cn) : sel4(Q0, cn);
            int lb    = tile ? isel4(lr1, cn) : isel4(lr0, cn);
            int pr = wavebase + g * 4 + cn + tile * 16;
            // nll = ln2 * (log2 T - Q2 + LS*log2 z_lab)
            float nll = LN2F * (__log2f(T) - Q + LOGIT_SCALE * __log2f(cxl));
            float pt = wsro[YT_OFF + lb], pn = wsro[XN_OFF + lb], ap = wsro[AP_OFF + lb];
            float num = fmaf(-cxl, pt, xts);              // y_time + c_xyl*x_time
            float den = pn * __builtin_amdgcn_sqrtf(fmaxf(fmaf(cxl, cxl, -1.f), 0.f));
            float ain = num * __builtin_amdgcn_rcpf(den + EPSF);
            ain = fminf(fmaxf(ain, -1.f + EPSF), 1.f - EPSF);
            // branchless acos: A&S 4.4.45, |err| <= 6.7e-5 rad
            float ax = fabsf(ain);
            float p = fmaf(fmaf(fmaf(-0.0187293f, ax, 0.0742610f), ax, -0.2121144f),
                           ax, 1.5707288f);
            float rr = __builtin_amdgcn_sqrtf(1.f - ax) * p;
            float ac = ain < 0.f ? 3.14159265358979f - rr : rr;
            float ent = fmaxf(ac - ap, 0.f);
            float vl = mask[pr] ? 0.f : 1.f;
            v_nll += nll * vl; v_ent += ent * vl; valid += vl;
        }
    }

    #pragma unroll
    for (int o = 32; o >= 1; o >>= 1) {
        v_nll += __shfl_down(v_nll, o, 64);
        v_ent += __shfl_down(v_ent, o, 64);
        valid += __shfl_down(valid, o, 64);
    }
    __shared__ float red[3][16];
    if (lane == 0) { red[0][wid] = v_nll; red[1][wid] = v_ent; red[2][wid] = valid; }
    __syncthreads();
    if (tid == 0) {
        float a = 0.f, b = 0.f, c = 0.f;
        #pragma unroll
        for (int w = 0; w < 16; w++) { a += red[0][w]; b += red[1][w]; c += red[2][w]; }
        blkout[blockIdx.x] = make_float4(a, b, c, 0.f);
    }
}

__global__ __launch_bounds__(1024) void reduce_kernel(const float4* __restrict__ blk,
                                                      float* __restrict__ out) {
    float a = 0.f, b = 0.f, c = 0.f;
    for (int i = threadIdx.x; i < NBLK; i += 1024) {
        float4 v = blk[i];
        a += v.x; b += v.y; c += v.z;
    }
    #pragma unroll
    for (int o = 32; o >= 1; o >>= 1) {
        a += __shfl_down(a, o, 64);
        b += __shfl_down(b, o, 64);
        c += __shfl_down(c, o, 64);
    }
    __shared__ float red[3][16];
    int wid = threadIdx.x >> 6, lane = threadIdx.x & 63;
    if (lane == 0) { red[0][wid] = a; red[1][wid] = b; red[2][wid] = c; }
    __syncthreads();
    if (threadIdx.x == 0) {
        float A = 0.f, B = 0.f, C = 0.f;
        #pragma unroll
        for (int w = 0; w < 16; w++) { A += red[0][w]; B += red[1][w]; C += red[2][w]; }
        float n = fmaxf(C, 1.f);
        out[0] = A / n + ENTAIL_WEIGHT * (B / n);
    }
}

extern "C" void kernel_launch(void* const* d_in, const int* in_sizes, int n_in,
                              void* d_out, int out_size, void* d_ws, size_t ws_size,
                              hipStream_t stream) {
    const float* feats  = (const float*)d_in[0];
    const float* protos = (const float*)d_in[1];
    const int* labels   = (const int*)d_in[2];
    const unsigned char* mask = (const unsigned char*)d_in[3];  // numpy bool = 1 byte
    float* ws = (float*)d_ws;

    proto_kernel<<<1, 256, 0, stream>>>(protos, ws);

    int npix = in_sizes[2];                 // B*H*W = 524288
    int nblk = npix / 512;                  // 16 waves/block, 32 pixels/wave
    main_kernel<<<nblk, 1024, 0, stream>>>(feats, labels, mask, ws,
                                           (float4*)(ws + BLK_OFF));
    reduce_kernel<<<1, 1024, 0, stream>>>((const float4*)(ws + BLK_OFF), (float*)d_out);
}

// Round 7
// 211.284 us; speedup vs baseline: 1.3926x; 1.0646x over previous
//
#include <hip/hip_runtime.h>
#include <math.h>

#define EPSF 1e-8f
#define SINH_MAXF 11.090354888959125f
#define IMAGE_ALPHA 0.25f
#define TEXT_ALPHA (1.0f/0.6f)
#define LOGIT_SCALE (1.0f/0.07f)
#define LN2F 0.6931471805599453f
#define SLN (LOGIT_SCALE*LN2F)
#define ENTAIL_WEIGHT 0.2f
#define NCLS 151
#define NPAD 160
#define DIM 64
#define NBLK 4096

// ws float offsets
#define LMIN_OFF 8   // log2(2*min_c y_time)
#define YT_OFF 16
#define XN_OFF (YT_OFF + NPAD)
#define AP_OFF (XN_OFF + NPAD)
#define BT_OFF 512                    // bf16 protos, MFMA-fragment order, 20480 B
#define BLK_OFF (BT_OFF + NPAD*DIM/2) // per-block float4 partials

// native exp2 (v_exp_f32) if the builtin exists; otherwise equivalent fallback
#if __has_builtin(__builtin_amdgcn_exp2f)
#define EXP2F(x) __builtin_amdgcn_exp2f(x)
#else
#define EXP2F(x) __expf((x) * LN2F)
#endif

typedef __attribute__((ext_vector_type(8))) short bf16x8;
typedef __attribute__((ext_vector_type(4))) float f32x4;

__device__ inline unsigned short f2bf(float f) {      // RNE (cold path only)
    unsigned int u = __float_as_uint(f);
    return (unsigned short)((u + 0x7FFFu + ((u >> 16) & 1u)) >> 16);
}
// pack trunc-bf16(hi) , trunc-bf16(lo) into one dword: 1 v_perm_b32
__device__ inline unsigned int pack_bf_trunc(float hi, float lo) {
    return __builtin_amdgcn_perm(__float_as_uint(hi), __float_as_uint(lo), 0x07060302u);
}
__device__ inline float sel4(const float* a, int i) {
    return i == 0 ? a[0] : i == 1 ? a[1] : i == 2 ? a[2] : a[3];
}

// Single block, 16 lanes per class. Writes protos in MFMA B-fragment order:
// 16B unit index = t*128 + half*64 + (g*16+cn), element j: class t*16+cn, dim half*32+g*8+j
// Lane li (0..15) of class group owns dims li*4..li*4+3:
//   half = li>>3, g = (li>>1)&3, j0 = (li&1)*4  ->  two dwords at unit*4 + (li&1)*2
__global__ __launch_bounds__(256) void proto_kernel(const float* __restrict__ protos,
                                                    float* __restrict__ ws) {
    int tid = threadIdx.x;
    int grp = tid >> 4, li = tid & 15;
    unsigned int* btu = (unsigned int*)(ws + BT_OFF);
    __shared__ float sYT[NPAD];
    #pragma unroll 2
    for (int t = 0; t < 10; t++) {
        int c = t * 16 + grp;
        float4 p4 = make_float4(0.f, 0.f, 0.f, 0.f);
        if (c < NCLS) p4 = ((const float4*)protos)[c * 16 + li];
        float vx = p4.x * TEXT_ALPHA, vy = p4.y * TEXT_ALPHA,
              vz = p4.z * TEXT_ALPHA, vw = p4.w * TEXT_ALPHA;
        float n2 = vx*vx + vy*vy + vz*vz + vw*vw;
        #pragma unroll
        for (int m = 8; m >= 1; m >>= 1) n2 += __shfl_xor(n2, m, 64);
        float rc = __builtin_amdgcn_sqrtf(n2);
        float rr = fminf(fmaxf(rc, EPSF), SINH_MAXF);
        float e = __expf(rr);
        float sh = 0.5f * (e - __builtin_amdgcn_rcpf(e));
        float sc = sh * __builtin_amdgcn_rcpf(fmaxf(rc, EPSF));
        unsigned int u0, u1;
        float yt, xn, ap;
        if (c < NCLS) {
            u0 = (unsigned int)f2bf(sc * vx) | ((unsigned int)f2bf(sc * vy) << 16);
            u1 = (unsigned int)f2bf(sc * vz) | ((unsigned int)f2bf(sc * vw) << 16);
            xn = sc * rc;
            yt = __builtin_amdgcn_sqrtf(fmaf(xn, xn, 1.f));
            float ai = fminf(fmaxf(0.2f / (xn + EPSF), -1.f + EPSF), 1.f - EPSF);
            ap = asinf(ai);
        } else {
            u0 = 0u; u1 = 0u; yt = 2e18f; xn = 1.f; ap = 0.f;
        }
        int unit = t * 128 + (li >> 3) * 64 + ((li >> 1) & 3) * 16 + grp;
        btu[unit * 4 + (li & 1) * 2]     = u0;
        btu[unit * 4 + (li & 1) * 2 + 1] = u1;
        if (li == 0) {
            ws[YT_OFF + c] = yt; ws[XN_OFF + c] = xn; ws[AP_OFF + c] = ap;
            sYT[c] = yt;
        }
    }
    __syncthreads();
    if (tid < 64) {
        float m = 1e30f;
        for (int c = tid; c < NCLS; c += 64) m = fminf(m, sYT[c]);
        #pragma unroll
        for (int k = 32; k >= 1; k >>= 1) m = fminf(m, __shfl_xor(m, k, 64));
        if (tid == 0) ws[LMIN_OFF] = __log2f(2.f * m);
    }
}

struct PixA { bf16x8 q0, q1; float xt, Q; };

__device__ inline PixA stage_pixel(const float4* fp, float lmin2) {
    float4 f0 = fp[0], f1 = fp[1], f2 = fp[8], f3 = fp[9];   // raw feats
    float n2r = f0.x*f0.x + f0.y*f0.y + f0.z*f0.z + f0.w*f0.w
              + f1.x*f1.x + f1.y*f1.y + f1.z*f1.z + f1.w*f1.w
              + f2.x*f2.x + f2.y*f2.y + f2.z*f2.z + f2.w*f2.w
              + f3.x*f3.x + f3.y*f3.y + f3.z*f3.z + f3.w*f3.w;
    n2r += __shfl_xor(n2r, 16, 64);
    n2r += __shfl_xor(n2r, 32, 64);      // 4 owner-lanes of this pixel have full ||feat||^2
    float rc = IMAGE_ALPHA * __builtin_amdgcn_sqrtf(n2r);   // ||alpha*feat||
    float rr = fminf(fmaxf(rc, EPSF), SINH_MAXF);
    float e = __expf(rr);
    float sh = 0.5f * (e - __builtin_amdgcn_rcpf(e));
    float sc = sh * __builtin_amdgcn_rcpf(fmaxf(rc, EPSF));
    float xn = sc * rc;
    float k = sc * IMAGE_ALPHA;          // combined scale on raw feats
    PixA r;
    r.xt = __builtin_amdgcn_sqrtf(fmaf(xn, xn, 1.f));
    // log2-domain constant: Q2 = (M0 - SLN)/ln2 so inner eval is one native exp2
    r.Q = LOGIT_SCALE * (lmin2 - __log2f(r.xt + xn) - 1.0f);
    unsigned int* q0u = (unsigned int*)&r.q0;
    unsigned int* q1u = (unsigned int*)&r.q1;
    q0u[0] = pack_bf_trunc(k*f0.y, k*f0.x);
    q0u[1] = pack_bf_trunc(k*f0.w, k*f0.z);
    q0u[2] = pack_bf_trunc(k*f1.y, k*f1.x);
    q0u[3] = pack_bf_trunc(k*f1.w, k*f1.z);
    q1u[0] = pack_bf_trunc(k*f2.y, k*f2.x);
    q1u[1] = pack_bf_trunc(k*f2.w, k*f2.z);
    q1u[2] = pack_bf_trunc(k*f3.y, k*f3.x);
    q1u[3] = pack_bf_trunc(k*f3.w, k*f3.z);
    return r;
}

// Process ONE 16-pixel tile (pixels tilebase..tilebase+15) for this wave.
// Registers live: one PixA (8), xtr/Q (8), packed labels (1), ss/sv (8) — about half
// the footprint of the old interleaved two-tile body.
__device__ __forceinline__ void process_tile16(
    const float* __restrict__ feats, const int* __restrict__ labels,
    const unsigned char* __restrict__ mask, const float* __restrict__ wsro,
    const uint4* sBT, const float* sYT, float lmin2,
    int tilebase, int lane, int cn, int g,
    float& v_nll, float& v_ent, float& valid)
{
    int pix = tilebase + cn;
    PixA A = stage_pixel((const float4*)(feats + (size_t)pix * DIM + g * 8), lmin2);
    int lab = labels[pix];

    float xtr[4], Q[4];
    int lr[4];
    #pragma unroll
    for (int r = 0; r < 4; r++) {
        int src = g * 4 + r;
        xtr[r] = __shfl(A.xt, src, 64);
        Q[r]   = __shfl(A.Q, src, 64);
        lr[r]  = __shfl(lab, src, 64);
    }

    float ss[4] = {0,0,0,0}, sv[4] = {0,0,0,0};   // label-z saved on owning lane

    #pragma unroll 2
    for (int t = 0; t < 10; t++) {
        uint4 u0 = sBT[t * 128 + lane];
        uint4 u1 = sBT[t * 128 + 64 + lane];
        bf16x8 bq0 = __builtin_bit_cast(bf16x8, u0);
        bf16x8 bq1 = __builtin_bit_cast(bf16x8, u1);
        float yt = sYT[t * 16 + cn];
        int cls = t * 16 + cn;
        f32x4 d = {0,0,0,0};
        d = __builtin_amdgcn_mfma_f32_16x16x32_bf16(A.q0, bq0, d, 0, 0, 0);
        d = __builtin_amdgcn_mfma_f32_16x16x32_bf16(A.q1, bq1, d, 0, 0, 0);
        #pragma unroll
        for (int r = 0; r < 4; r++) {
            float c = fmaf(xtr[r], yt, -d[r]);     // z = x_time*y_time - dot (>= ~9e4)
            if (lr[r] == cls) sv[r] = c;
            ss[r] += EXP2F(fmaf(-LOGIT_SCALE, __log2f(c), Q[r]));  // 2^(logit2 - M02)
        }
    }

    // fetch label-z via shfl gather, then sum-reduce ss across the 16-lane class dim
    int gbase = lane & 48;
    float cx[4];
    #pragma unroll
    for (int r = 0; r < 4; r++)
        cx[r] = __shfl(sv[r], gbase + (lr[r] & 15), 64);
    #pragma unroll
    for (int k = 1; k < 16; k <<= 1) {
        #pragma unroll
        for (int r = 0; r < 4; r++) ss[r] += __shfl_xor(ss[r], k, 64);
    }

    if (cn < 4) {
        float T   = sel4(ss, cn);
        float cxl = sel4(cx, cn);
        float xts = sel4(xtr, cn);
        float Qv  = sel4(Q, cn);
        int lb = cn == 0 ? lr[0] : cn == 1 ? lr[1] : cn == 2 ? lr[2] : lr[3];
        int pr = tilebase + g * 4 + cn;
        // nll = ln2 * (log2 T - Q2 + LS*log2 z_lab)
        float nll = LN2F * (__log2f(T) - Qv + LOGIT_SCALE * __log2f(cxl));
        float pt = wsro[YT_OFF + lb], pn = wsro[XN_OFF + lb], ap = wsro[AP_OFF + lb];
        float num = fmaf(-cxl, pt, xts);              // y_time + c_xyl*x_time
        float den = pn * __builtin_amdgcn_sqrtf(fmaxf(fmaf(cxl, cxl, -1.f), 0.f));
        float ain = num * __builtin_amdgcn_rcpf(den + EPSF);
        ain = fminf(fmaxf(ain, -1.f + EPSF), 1.f - EPSF);
        // branchless acos: A&S 4.4.45, |err| <= 6.7e-5 rad
        float ax = fabsf(ain);
        float p = fmaf(fmaf(fmaf(-0.0187293f, ax, 0.0742610f), ax, -0.2121144f),
                       ax, 1.5707288f);
        float rr = __builtin_amdgcn_sqrtf(1.f - ax) * p;
        float ac = ain < 0.f ? 3.14159265358979f - rr : rr;
        float ent = fmaxf(ac - ap, 0.f);
        float vl = mask[pr] ? 0.f : 1.f;
        v_nll += nll * vl; v_ent += ent * vl; valid += vl;
    }
}

__global__ __launch_bounds__(256) void main_kernel(
    const float* __restrict__ feats, const int* __restrict__ labels,
    const unsigned char* __restrict__ mask, const float* __restrict__ wsro,
    float4* __restrict__ blkout)
{
    __shared__ uint4 sBT[1280];     // 20480 B, fragment order
    __shared__ float sYT[NPAD];
    int tid = threadIdx.x;
    const uint4* btg = (const uint4*)(wsro + BT_OFF);
    #pragma unroll
    for (int k = 0; k < 5; k++) sBT[tid + k * 256] = btg[tid + k * 256];
    if (tid < NPAD) sYT[tid] = wsro[YT_OFF + tid];
    __syncthreads();

    int wid = tid >> 6, lane = tid & 63;
    int cn = lane & 15, g = lane >> 4;
    int wavebase = (blockIdx.x * 4 + wid) * 32;
    float lmin2 = wsro[LMIN_OFF];

    float v_nll = 0.f, v_ent = 0.f, valid = 0.f;
    process_tile16(feats, labels, mask, wsro, sBT, sYT, lmin2,
                   wavebase, lane, cn, g, v_nll, v_ent, valid);
    process_tile16(feats, labels, mask, wsro, sBT, sYT, lmin2,
                   wavebase + 16, lane, cn, g, v_nll, v_ent, valid);

    #pragma unroll
    for (int o = 32; o >= 1; o >>= 1) {
        v_nll += __shfl_down(v_nll, o, 64);
        v_ent += __shfl_down(v_ent, o, 64);
        valid += __shfl_down(valid, o, 64);
    }
    __shared__ float red[3][4];
    if (lane == 0) { red[0][wid] = v_nll; red[1][wid] = v_ent; red[2][wid] = valid; }
    __syncthreads();
    if (tid == 0) {
        float a = 0.f, b = 0.f, c = 0.f;
        #pragma unroll
        for (int w = 0; w < 4; w++) { a += red[0][w]; b += red[1][w]; c += red[2][w]; }
        blkout[blockIdx.x] = make_float4(a, b, c, 0.f);
    }
}

__global__ __launch_bounds__(1024) void reduce_kernel(const float4* __restrict__ blk,
                                                      float* __restrict__ out) {
    float a = 0.f, b = 0.f, c = 0.f;
    for (int i = threadIdx.x; i < NBLK; i += 1024) {
        float4 v = blk[i];
        a += v.x; b += v.y; c += v.z;
    }
    #pragma unroll
    for (int o = 32; o >= 1; o >>= 1) {
        a += __shfl_down(a, o, 64);
        b += __shfl_down(b, o, 64);
        c += __shfl_down(c, o, 64);
    }
    __shared__ float red[3][16];
    int wid = threadIdx.x >> 6, lane = threadIdx.x & 63;
    if (lane == 0) { red[0][wid] = a; red[1][wid] = b; red[2][wid] = c; }
    __syncthreads();
    if (threadIdx.x == 0) {
        float A = 0.f, B = 0.f, C = 0.f;
        #pragma unroll
        for (int w = 0; w < 16; w++) { A += red[0][w]; B += red[1][w]; C += red[2][w]; }
        float n = fmaxf(C, 1.f);
        out[0] = A / n + ENTAIL_WEIGHT * (B / n);
    }
}

extern "C" void kernel_launch(void* const* d_in, const int* in_sizes, int n_in,
                              void* d_out, int out_size, void* d_ws, size_t ws_size,
                              hipStream_t stream) {
    const float* feats  = (const float*)d_in[0];
    const float* protos = (const float*)d_in[1];
    const int* labels   = (const int*)d_in[2];
    const unsigned char* mask = (const unsigned char*)d_in[3];  // numpy bool = 1 byte
    float* ws = (float*)d_ws;

    proto_kernel<<<1, 256, 0, stream>>>(protos, ws);

    int npix = in_sizes[2];                 // B*H*W = 524288
    int nblk = npix / 128;                  // 4 waves/block, 32 pixels/wave
    main_kernel<<<nblk, 256, 0, stream>>>(feats, labels, mask, ws,
                                          (float4*)(ws + BLK_OFF));
    reduce_kernel<<<1, 1024, 0, stream>>>((const float4*)(ws + BLK_OFF), (float*)d_out);
}

// Round 9
// 210.144 us; speedup vs baseline: 1.4002x; 1.0054x over previous
//
#include <hip/hip_runtime.h>
#include <math.h>

#define EPSF 1e-8f
#define SINH_MAXF 11.090354888959125f
#define IMAGE_ALPHA 0.25f
#define TEXT_ALPHA (1.0f/0.6f)
#define LOGIT_SCALE (1.0f/0.07f)
#define LN2F 0.6931471805599453f
#define SLN (LOGIT_SCALE*LN2F)
#define ENTAIL_WEIGHT 0.2f
#define NCLS 151
#define NPAD 160
#define DIM 64
#define NBLK 4096

// ws float offsets
#define LMIN_OFF 8   // log2(2*min_c y_time)
#define YT_OFF 16
#define XN_OFF (YT_OFF + NPAD)
#define AP_OFF (XN_OFF + NPAD)
#define BT_OFF 512                    // bf16 protos, MFMA-fragment order, 20480 B
#define BLK_OFF (BT_OFF + NPAD*DIM/2) // per-block float4 partials

// native exp2 (v_exp_f32) if the builtin exists; otherwise equivalent fallback
#if __has_builtin(__builtin_amdgcn_exp2f)
#define EXP2F(x) __builtin_amdgcn_exp2f(x)
#else
#define EXP2F(x) __expf((x) * LN2F)
#endif

typedef __attribute__((ext_vector_type(8))) short bf16x8;
typedef __attribute__((ext_vector_type(4))) float f32x4;

__device__ inline unsigned short f2bf(float f) {      // RNE (cold path only)
    unsigned int u = __float_as_uint(f);
    return (unsigned short)((u + 0x7FFFu + ((u >> 16) & 1u)) >> 16);
}
// pack trunc-bf16(hi) , trunc-bf16(lo) into one dword: 1 v_perm_b32
__device__ inline unsigned int pack_bf_trunc(float hi, float lo) {
    return __builtin_amdgcn_perm(__float_as_uint(hi), __float_as_uint(lo), 0x07060302u);
}
__device__ inline float sel4(const float* a, int i) {
    return i == 0 ? a[0] : i == 1 ? a[1] : i == 2 ? a[2] : a[3];
}
__device__ inline int isel4(const int* a, int i) {
    return i == 0 ? a[0] : i == 1 ? a[1] : i == 2 ? a[2] : a[3];
}

// ---- DPP reduction helpers: VALU-rate cross-lane adds, no DS pipe ----
// CTRL must be a compile-time constant -> template parameter (R8 compile fix).
template <int CTRL>
__device__ __forceinline__ float dpp_add(float v) {
    int t = __builtin_amdgcn_update_dpp(0, __float_as_int(v), CTRL, 0xf, 0xf, true);
    return v + __int_as_float(t);
}
// 16-lane (row) sum; association identical to the xor1/2/4/8 butterfly for
// lanes 0-3 of each row16 (the only consumers). quad_perm[1,0,3,2]=0xB1 (xor1),
// quad_perm[2,3,0,1]=0x4E (xor2), row_shl:4=0x104, row_shl:8=0x108.
__device__ __forceinline__ float row16_sum_lo(float v) {
    v = dpp_add<0xB1>(v);
    v = dpp_add<0x4E>(v);
    v = dpp_add<0x104>(v);
    v = dpp_add<0x108>(v);
    return v;   // valid on lanes (lane&15) < 4
}

// Single block, 16 lanes per class. Writes protos in MFMA B-fragment order:
// 16B unit index = t*128 + half*64 + (g*16+cn), element j: class t*16+cn, dim half*32+g*8+j
// Lane li (0..15) of class group owns dims li*4..li*4+3:
//   half = li>>3, g = (li>>1)&3, j0 = (li&1)*4  ->  two dwords at unit*4 + (li&1)*2
__global__ __launch_bounds__(256) void proto_kernel(const float* __restrict__ protos,
                                                    float* __restrict__ ws) {
    int tid = threadIdx.x;
    int grp = tid >> 4, li = tid & 15;
    unsigned int* btu = (unsigned int*)(ws + BT_OFF);
    __shared__ float sYT[NPAD];
    #pragma unroll 2
    for (int t = 0; t < 10; t++) {
        int c = t * 16 + grp;
        float4 p4 = make_float4(0.f, 0.f, 0.f, 0.f);
        if (c < NCLS) p4 = ((const float4*)protos)[c * 16 + li];
        float vx = p4.x * TEXT_ALPHA, vy = p4.y * TEXT_ALPHA,
              vz = p4.z * TEXT_ALPHA, vw = p4.w * TEXT_ALPHA;
        float n2 = vx*vx + vy*vy + vz*vz + vw*vw;
        #pragma unroll
        for (int m = 8; m >= 1; m >>= 1) n2 += __shfl_xor(n2, m, 64);
        float rc = __builtin_amdgcn_sqrtf(n2);
        float rr = fminf(fmaxf(rc, EPSF), SINH_MAXF);
        float e = __expf(rr);
        float sh = 0.5f * (e - __builtin_amdgcn_rcpf(e));
        float sc = sh * __builtin_amdgcn_rcpf(fmaxf(rc, EPSF));
        unsigned int u0, u1;
        float yt, xn, ap;
        if (c < NCLS) {
            u0 = (unsigned int)f2bf(sc * vx) | ((unsigned int)f2bf(sc * vy) << 16);
            u1 = (unsigned int)f2bf(sc * vz) | ((unsigned int)f2bf(sc * vw) << 16);
            xn = sc * rc;
            yt = __builtin_amdgcn_sqrtf(fmaf(xn, xn, 1.f));
            float ai = fminf(fmaxf(0.2f / (xn + EPSF), -1.f + EPSF), 1.f - EPSF);
            ap = asinf(ai);
        } else {
            u0 = 0u; u1 = 0u; yt = 2e18f; xn = 1.f; ap = 0.f;
        }
        int unit = t * 128 + (li >> 3) * 64 + ((li >> 1) & 3) * 16 + grp;
        btu[unit * 4 + (li & 1) * 2]     = u0;
        btu[unit * 4 + (li & 1) * 2 + 1] = u1;
        if (li == 0) {
            ws[YT_OFF + c] = yt; ws[XN_OFF + c] = xn; ws[AP_OFF + c] = ap;
            sYT[c] = yt;
        }
    }
    __syncthreads();
    if (tid < 64) {
        float m = 1e30f;
        for (int c = tid; c < NCLS; c += 64) m = fminf(m, sYT[c]);
        #pragma unroll
        for (int k = 32; k >= 1; k >>= 1) m = fminf(m, __shfl_xor(m, k, 64));
        if (tid == 0) ws[LMIN_OFF] = __log2f(2.f * m);
    }
}

struct PixA { bf16x8 q0, q1; float xt, Q; };

__device__ inline PixA stage_pixel(const float4* fp, float lmin2) {
    float4 f0 = fp[0], f1 = fp[1], f2 = fp[8], f3 = fp[9];   // raw feats
    float n2r = f0.x*f0.x + f0.y*f0.y + f0.z*f0.z + f0.w*f0.w
              + f1.x*f1.x + f1.y*f1.y + f1.z*f1.z + f1.w*f1.w
              + f2.x*f2.x + f2.y*f2.y + f2.z*f2.z + f2.w*f2.w
              + f3.x*f3.x + f3.y*f3.y + f3.z*f3.z + f3.w*f3.w;
    n2r += __shfl_xor(n2r, 16, 64);
    n2r += __shfl_xor(n2r, 32, 64);      // 4 owner-lanes of this pixel have full ||feat||^2
    float rc = IMAGE_ALPHA * __builtin_amdgcn_sqrtf(n2r);   // ||alpha*feat||
    float rr = fminf(fmaxf(rc, EPSF), SINH_MAXF);
    float e = __expf(rr);
    float sh = 0.5f * (e - __builtin_amdgcn_rcpf(e));
    float sc = sh * __builtin_amdgcn_rcpf(fmaxf(rc, EPSF));
    float xn = sc * rc;
    float k = sc * IMAGE_ALPHA;          // combined scale on raw feats
    PixA r;
    r.xt = __builtin_amdgcn_sqrtf(fmaf(xn, xn, 1.f));
    // log2-domain constant: Q2 = (M0 - SLN)/ln2 so inner eval is one native exp2
    r.Q = LOGIT_SCALE * (lmin2 - __log2f(r.xt + xn) - 1.0f);
    unsigned int* q0u = (unsigned int*)&r.q0;
    unsigned int* q1u = (unsigned int*)&r.q1;
    q0u[0] = pack_bf_trunc(k*f0.y, k*f0.x);
    q0u[1] = pack_bf_trunc(k*f0.w, k*f0.z);
    q0u[2] = pack_bf_trunc(k*f1.y, k*f1.x);
    q0u[3] = pack_bf_trunc(k*f1.w, k*f1.z);
    q1u[0] = pack_bf_trunc(k*f2.y, k*f2.x);
    q1u[1] = pack_bf_trunc(k*f2.w, k*f2.z);
    q1u[2] = pack_bf_trunc(k*f3.y, k*f3.x);
    q1u[3] = pack_bf_trunc(k*f3.w, k*f3.z);
    return r;
}

__global__ __launch_bounds__(256) void main_kernel(
    const float* __restrict__ feats, const int* __restrict__ labels,
    const unsigned char* __restrict__ mask, const float* __restrict__ wsro,
    float4* __restrict__ blkout)
{
    __shared__ uint4 sBT[1280];     // 20480 B, fragment order
    __shared__ float sYT[NPAD];
    __shared__ float sXN[NPAD];     // epilogue tables in LDS: DS latency instead of
    __shared__ float sAP[NPAD];     // ~200cy global loads on the serial tail
    int tid = threadIdx.x;
    const uint4* btg = (const uint4*)(wsro + BT_OFF);
    #pragma unroll
    for (int k = 0; k < 5; k++) sBT[tid + k * 256] = btg[tid + k * 256];
    if (tid < NPAD) {
        sYT[tid] = wsro[YT_OFF + tid];
        sXN[tid] = wsro[XN_OFF + tid];
        sAP[tid] = wsro[AP_OFF + tid];
    }
    __syncthreads();

    int wid = tid >> 6, lane = tid & 63;
    int cn = lane & 15, g = lane >> 4;
    int wavebase = (blockIdx.x * 4 + wid) * 32;
    int pix0 = wavebase + cn, pix1 = pix0 + 16;
    float lmin2 = wsro[LMIN_OFF];

    PixA A0 = stage_pixel((const float4*)(feats + (size_t)pix0 * DIM + g * 8), lmin2);
    PixA A1 = stage_pixel((const float4*)(feats + (size_t)pix1 * DIM + g * 8), lmin2);
    int lab0 = labels[pix0], lab1 = labels[pix1];

    float xtr0[4], Q0[4], xtr1[4], Q1[4];
    int lr0[4], lr1[4];
    #pragma unroll
    for (int r = 0; r < 4; r++) {
        int src = g * 4 + r;
        xtr0[r] = __shfl(A0.xt, src, 64); Q0[r] = __shfl(A0.Q, src, 64);
        lr0[r]  = __shfl(lab0, src, 64);
        xtr1[r] = __shfl(A1.xt, src, 64); Q1[r] = __shfl(A1.Q, src, 64);
        lr1[r]  = __shfl(lab1, src, 64);
    }

    float ss0[4] = {0,0,0,0}, ss1[4] = {0,0,0,0};
    float sv0[4] = {0,0,0,0}, sv1[4] = {0,0,0,0};   // label-z saved on owning lane

    #pragma unroll 2
    for (int t = 0; t < 10; t++) {
        uint4 u0 = sBT[t * 128 + lane];
        uint4 u1 = sBT[t * 128 + 64 + lane];
        bf16x8 bq0 = __builtin_bit_cast(bf16x8, u0);
        bf16x8 bq1 = __builtin_bit_cast(bf16x8, u1);
        float yt = sYT[t * 16 + cn];
        int cls = t * 16 + cn;
        f32x4 d0 = {0,0,0,0}, d1 = {0,0,0,0};
        d0 = __builtin_amdgcn_mfma_f32_16x16x32_bf16(A0.q0, bq0, d0, 0, 0, 0);
        d0 = __builtin_amdgcn_mfma_f32_16x16x32_bf16(A0.q1, bq1, d0, 0, 0, 0);
        d1 = __builtin_amdgcn_mfma_f32_16x16x32_bf16(A1.q0, bq0, d1, 0, 0, 0);
        d1 = __builtin_amdgcn_mfma_f32_16x16x32_bf16(A1.q1, bq1, d1, 0, 0, 0);
        #pragma unroll
        for (int r = 0; r < 4; r++) {
            float c0 = fmaf(xtr0[r], yt, -d0[r]);         // z = x_time*y_time - dot
            if (lr0[r] == cls) sv0[r] = c0;
            ss0[r] += EXP2F(fmaf(-LOGIT_SCALE, __log2f(c0), Q0[r]));  // 2^(logit2 - M02)
            float c1 = fmaf(xtr1[r], yt, -d1[r]);
            if (lr1[r] == cls) sv1[r] = c1;
            ss1[r] += EXP2F(fmaf(-LOGIT_SCALE, __log2f(c1), Q1[r]));
        }
    }

    // fetch label-z via shfl gather (runtime index, must stay bpermute)
    int gbase = lane & 48;
    float cx0[4], cx1[4];
    #pragma unroll
    for (int r = 0; r < 4; r++) {
        cx0[r] = __shfl(sv0[r], gbase + (lr0[r] & 15), 64);
        cx1[r] = __shfl(sv1[r], gbase + (lr1[r] & 15), 64);
    }
    // 16-lane class-dim sum via DPP (VALU), valid on lanes cn<4 (the consumers)
    #pragma unroll
    for (int r = 0; r < 4; r++) {
        ss0[r] = row16_sum_lo(ss0[r]);
        ss1[r] = row16_sum_lo(ss1[r]);
    }

    float v_nll = 0.f, v_ent = 0.f, valid = 0.f;
    if (cn < 4) {
        #pragma unroll
        for (int tile = 0; tile < 2; tile++) {
            float T   = tile ? sel4(ss1, cn) : sel4(ss0, cn);
            float cxl = tile ? sel4(cx1, cn) : sel4(cx0, cn);
            float xts = tile ? sel4(xtr1, cn) : sel4(xtr0, cn);
            float Q   = tile ? sel4(Q1, cn) : sel4(Q0, cn);
            int lb    = tile ? isel4(lr1, cn) : isel4(lr0, cn);
            int pr = wavebase + g * 4 + cn + tile * 16;
            // nll = ln2 * (log2 T - Q2 + LS*log2 z_lab)
            float nll = LN2F * (__log2f(T) - Q + LOGIT_SCALE * __log2f(cxl));
            float pt = sYT[lb], pn = sXN[lb], ap = sAP[lb];
            float num = fmaf(-cxl, pt, xts);              // y_time + c_xyl*x_time
            float den = pn * __builtin_amdgcn_sqrtf(fmaxf(fmaf(cxl, cxl, -1.f), 0.f));
            float ain = num * __builtin_amdgcn_rcpf(den + EPSF);
            ain = fminf(fmaxf(ain, -1.f + EPSF), 1.f - EPSF);
            // branchless acos: A&S 4.4.45, |err| <= 6.7e-5 rad
            float ax = fabsf(ain);
            float p = fmaf(fmaf(fmaf(-0.0187293f, ax, 0.0742610f), ax, -0.2121144f),
                           ax, 1.5707288f);
            float rr = __builtin_amdgcn_sqrtf(1.f - ax) * p;
            float ac = ain < 0.f ? 3.14159265358979f - rr : rr;
            float ent = fmaxf(ac - ap, 0.f);
            float vl = mask[pr] ? 0.f : 1.f;
            v_nll += nll * vl; v_ent += ent * vl; valid += vl;
        }
    }

    // wave reduce: DPP row16 sum, then 2 cross-row shfls (vs 6 bpermute levels)
    v_nll = row16_sum_lo(v_nll);
    v_ent = row16_sum_lo(v_ent);
    valid = row16_sum_lo(valid);
    v_nll += __shfl_xor(v_nll, 16, 64); v_nll += __shfl_xor(v_nll, 32, 64);
    v_ent += __shfl_xor(v_ent, 16, 64); v_ent += __shfl_xor(v_ent, 32, 64);
    valid += __shfl_xor(valid, 16, 64); valid += __shfl_xor(valid, 32, 64);

    __shared__ float red[3][4];
    if (lane == 0) { red[0][wid] = v_nll; red[1][wid] = v_ent; red[2][wid] = valid; }
    __syncthreads();
    if (tid == 0) {
        float a = 0.f, b = 0.f, c = 0.f;
        #pragma unroll
        for (int w = 0; w < 4; w++) { a += red[0][w]; b += red[1][w]; c += red[2][w]; }
        blkout[blockIdx.x] = make_float4(a, b, c, 0.f);
    }
}

__global__ __launch_bounds__(1024) void reduce_kernel(const float4* __restrict__ blk,
                                                      float* __restrict__ out) {
    float a = 0.f, b = 0.f, c = 0.f;
    for (int i = threadIdx.x; i < NBLK; i += 1024) {
        float4 v = blk[i];
        a += v.x; b += v.y; c += v.z;
    }
    #pragma unroll
    for (int o = 32; o >= 1; o >>= 1) {
        a += __shfl_down(a, o, 64);
        b += __shfl_down(b, o, 64);
        c += __shfl_down(c, o, 64);
    }
    __shared__ float red[3][16];
    int wid = threadIdx.x >> 6, lane = threadIdx.x & 63;
    if (lane == 0) { red[0][wid] = a; red[1][wid] = b; red[2][wid] = c; }
    __syncthreads();
    if (threadIdx.x == 0) {
        float A = 0.f, B = 0.f, C = 0.f;
        #pragma unroll
        for (int w = 0; w < 16; w++) { A += red[0][w]; B += red[1][w]; C += red[2][w]; }
        float n = fmaxf(C, 1.f);
        out[0] = A / n + ENTAIL_WEIGHT * (B / n);
    }
}

extern "C" void kernel_launch(void* const* d_in, const int* in_sizes, int n_in,
                              void* d_out, int out_size, void* d_ws, size_t ws_size,
                              hipStream_t stream) {
    const float* feats  = (const float*)d_in[0];
    const float* protos = (const float*)d_in[1];
    const int* labels   = (const int*)d_in[2];
    const unsigned char* mask = (const unsigned char*)d_in[3];  // numpy bool = 1 byte
    float* ws = (float*)d_ws;

    proto_kernel<<<1, 256, 0, stream>>>(protos, ws);

    int npix = in_sizes[2];                 // B*H*W = 524288
    int nblk = npix / 128;                  // 4 waves/block, 32 pixels/wave
    main_kernel<<<nblk, 256, 0, stream>>>(feats, labels, mask, ws,
                                          (float4*)(ws + BLK_OFF));
    reduce_kernel<<<1, 1024, 0, stream>>>((const float4*)(ws + BLK_OFF), (float*)d_out);
}